// Round 3
// baseline (2037.650 us; speedup 1.0000x reference)
//
#include <hip/hip_runtime.h>
#include <stdint.h>

#define N_TOTAL  1327104     // 384*384*9
#define KPRE     12000
#define KPOST    2000
#define NPAD     12032       // KPRE padded to 64
#define WORDS    188         // 12032/64
#define CAND_CAP 16384
#define IMGLIM   6144.0f

// 9 base anchors (ratio-major, scale-minor). All centered at (7.5,7.5) so
// cx = col*16 + 8, cy = row*16 + 8 exactly; only (w,h) vary per anchor.
__constant__ float c_aw[9] = {184.f,368.f,736.f,128.f,256.f,512.f, 88.f,176.f,352.f};
__constant__ float c_ah[9] = { 96.f,192.f,384.f,128.f,256.f,512.f,176.f,352.f,704.f};

// block FMA contraction: numpy computes d*w (round) then +c (round)
__device__ __forceinline__ float mul_sep(float a, float b) {
    float r = a * b;
    asm volatile("" : "+v"(r));
    return r;
}

__device__ __forceinline__ void compute_box(int idx, const float4 d,
        float& ox0, float& oy0, float& ox1, float& oy1, bool& keep)
{
    int a    = idx % 9;
    int cell = idx / 9;
    int col  = cell % 384;
    int row  = cell / 384;
    float w = c_aw[a], h = c_ah[a];
    float cx = (float)(col * 16 + 8);
    float cy = (float)(row * 16 + 8);
    float pcx = mul_sep(d.x, w) + cx;
    float pcy = mul_sep(d.y, h) + cy;
    float pw = expf(d.z) * w;
    float ph = expf(d.w) * h;
    // 0.5f*pw is exact halving -> contraction-safe
    float x0 = pcx - 0.5f * pw;
    float y0 = pcy - 0.5f * ph;
    float x1 = pcx + 0.5f * pw;
    float y1 = pcy + 0.5f * ph;
    ox0 = fminf(fmaxf(x0, 0.f), IMGLIM);
    oy0 = fminf(fmaxf(y0, 0.f), IMGLIM);
    ox1 = fminf(fmaxf(x1, 0.f), IMGLIM);
    oy1 = fminf(fmaxf(y1, 0.f), IMGLIM);
    keep = ((ox1 - ox0) >= 16.f) && ((oy1 - oy0) >= 16.f);
}

__global__ void k_init(uint32_t* hist1, uint32_t* hist2, uint32_t* hist3,
                       uint32_t* state, uint32_t* sorted_anchor)
{
    int t = blockIdx.x * blockDim.x + threadIdx.x;
    if      (t < 2048) hist1[t] = 0;
    else if (t < 4096) hist2[t - 2048] = 0;
    else if (t < 5120) hist3[t - 4096] = 0;
    else if (t < 5136) state[t - 5120] = 0;
    int u = t - 5136;
    if (u >= 0 && u < NPAD) sorted_anchor[u] = 0xFFFFFFFFu;
}

// keys: score bits if box passes min-size filter else 0; + pass-1 histogram (top 11 bits)
__global__ void k_keys(const float* __restrict__ delta, const float* __restrict__ score,
                       uint32_t* __restrict__ keys, uint32_t* __restrict__ hist1)
{
    __shared__ uint32_t lh[2048];
    for (int t = threadIdx.x; t < 2048; t += blockDim.x) lh[t] = 0;
    __syncthreads();
    int idx = blockIdx.x * blockDim.x + threadIdx.x;
    if (idx < N_TOTAL) {
        float4 d = ((const float4*)delta)[idx];
        float x0, y0, x1, y1; bool keep;
        compute_box(idx, d, x0, y0, x1, y1, keep);
        float s = ((const float2*)score)[idx].y;
        uint32_t key = keep ? __float_as_uint(s) : 0u;   // s in [0,1): bits monotonic
        keys[idx] = key;
        atomicAdd(&lh[key >> 21], 1u);
    }
    __syncthreads();
    for (int t = threadIdx.x; t < 2048; t += blockDim.x) {
        uint32_t c = lh[t];
        if (c) atomicAdd(&hist1[t], c);
    }
}

__global__ void k_hist2(const uint32_t* __restrict__ keys, const uint32_t* __restrict__ state,
                        uint32_t* __restrict__ hist)
{
    __shared__ uint32_t lh[2048];
    for (int t = threadIdx.x; t < 2048; t += blockDim.x) lh[t] = 0;
    __syncthreads();
    uint32_t B1 = state[0];
    int idx = blockIdx.x * blockDim.x + threadIdx.x;
    if (idx < N_TOTAL) {
        uint32_t k = keys[idx];
        if ((k >> 21) == B1) atomicAdd(&lh[(k >> 10) & 0x7FFu], 1u);
    }
    __syncthreads();
    for (int t = threadIdx.x; t < 2048; t += blockDim.x) {
        uint32_t c = lh[t];
        if (c) atomicAdd(&hist[t], c);
    }
}

__global__ void k_hist3(const uint32_t* __restrict__ keys, const uint32_t* __restrict__ state,
                        uint32_t* __restrict__ hist)
{
    __shared__ uint32_t lh[1024];
    for (int t = threadIdx.x; t < 1024; t += blockDim.x) lh[t] = 0;
    __syncthreads();
    uint32_t pfx = state[2];
    int idx = blockIdx.x * blockDim.x + threadIdx.x;
    if (idx < N_TOTAL) {
        uint32_t k = keys[idx];
        if ((k >> 10) == pfx) atomicAdd(&lh[k & 0x3FFu], 1u);
    }
    __syncthreads();
    for (int t = threadIdx.x; t < 1024; t += blockDim.x) {
        uint32_t c = lh[t];
        if (c) atomicAdd(&hist[t], c);
    }
}

// find bin containing the K-th largest: parallel suffix-scan over bins
__global__ void k_scan(const uint32_t* __restrict__ hist, uint32_t* __restrict__ state,
                       int nbins, int pass)
{
    __shared__ uint32_t sh[2048];
    __shared__ uint32_t part[256];
    __shared__ uint32_t sB, sRem;
    int t = threadIdx.x;                 // 256 threads
    int seg = nbins >> 8;                // 8 or 4
    uint32_t K = (pass == 0) ? (uint32_t)KPRE : ((pass == 1) ? state[1] : state[3]);
    if (K == 0u) K = 1u;
    uint32_t local = 0;
    for (int i = 0; i < seg; ++i) {
        uint32_t h = hist[t * seg + i];
        sh[t * seg + i] = h;
        local += h;
    }
    part[t] = local;
    __syncthreads();
    // inclusive suffix sum over part[]
    for (int off = 1; off < 256; off <<= 1) {
        uint32_t v = part[t];
        uint32_t add = (t + off < 256) ? part[t + off] : 0u;
        __syncthreads();
        part[t] = v + add;
        __syncthreads();
    }
    uint32_t mine  = part[t];                         // sum of bins >= t*seg
    uint32_t below = (t + 1 < 256) ? part[t + 1] : 0; // sum of bins >= (t+1)*seg
    if (mine >= K && below < K) {                     // unique thread
        uint32_t cum = below;
        for (int i = seg - 1; i >= 0; --i) {
            uint32_t h = sh[t * seg + i];
            if (cum + h >= K) { sB = (uint32_t)(t * seg + i); sRem = K - cum; break; }
            cum += h;
        }
    }
    __syncthreads();
    if (t == 0) {
        uint32_t B = sB, rem = sRem;
        if      (pass == 0) { state[0] = B; state[1] = rem; }
        else if (pass == 1) { state[2] = (state[0] << 11) | B; state[3] = rem; }
        else                { state[4] = (state[2] << 10) | B; }
    }
}

// compact all keys >= threshold; wave-aggregated atomic (1 per active wave)
__global__ void k_compact(const uint32_t* __restrict__ keys, uint32_t* __restrict__ state,
                          uint64_t* __restrict__ cand)
{
    uint32_t T = state[4];
    int idx = blockIdx.x * blockDim.x + threadIdx.x;
    bool pred = false; uint32_t k = 0;
    if (idx < N_TOTAL) { k = keys[idx]; pred = (k >= T); }
    uint64_t bal = __ballot(pred);
    if (bal == 0ull) return;
    int lane = threadIdx.x & 63;
    int leader = __ffsll((unsigned long long)bal) - 1;
    uint32_t base = 0;
    if (lane == leader) base = atomicAdd(&state[5], (uint32_t)__popcll((unsigned long long)bal));
    base = (uint32_t)__shfl((int)base, leader, 64);
    if (pred) {
        uint64_t lower = (lane == 0) ? 0ull : (~0ull >> (64 - lane));
        uint32_t p = base + (uint32_t)__popcll((unsigned long long)(bal & lower));
        if (p < CAND_CAP)
            cand[p] = ((uint64_t)k << 32) | (uint64_t)(0xFFFFFFFFu - (uint32_t)idx);
    }
}

// exact rank sort: rank = #{j : key_j > key_i}; keys unique -> bijective
__global__ void k_ranksort(const uint64_t* __restrict__ cand, const uint32_t* __restrict__ state,
                           uint32_t* __restrict__ sorted_anchor)
{
    __shared__ uint64_t lk[2048];
    uint32_t M = min(state[5], (uint32_t)CAND_CAP);
    int i = blockIdx.x * blockDim.x + threadIdx.x;
    uint64_t mykey = (i < (int)M) ? cand[i] : 0ull;
    uint32_t rank = 0;
    for (uint32_t base = 0; base < M; base += 2048) {
        uint32_t chunk = min(2048u, M - base);
        __syncthreads();
        for (uint32_t t = threadIdx.x; t < chunk; t += blockDim.x) lk[t] = cand[base + t];
        __syncthreads();
        if (i < (int)M)
            for (uint32_t j = 0; j < chunk; ++j) rank += (lk[j] > mykey) ? 1u : 0u;
    }
    if (i < (int)M && rank < KPRE)
        sorted_anchor[rank] = 0xFFFFFFFFu - (uint32_t)(mykey & 0xFFFFFFFFull);
}

__global__ void k_boxes(const float* __restrict__ delta, const uint32_t* __restrict__ sorted_anchor,
                        float* __restrict__ bx0, float* __restrict__ by0,
                        float* __restrict__ bx1, float* __restrict__ by1,
                        float* __restrict__ bar)
{
    int r = blockIdx.x * blockDim.x + threadIdx.x;
    if (r >= NPAD) return;
    float x0 = 0.f, y0 = 0.f, x1 = 0.f, y1 = 0.f;
    if (r < KPRE) {
        uint32_t aidx = sorted_anchor[r];
        if (aidx < (uint32_t)N_TOTAL) {
            float4 d = ((const float4*)delta)[aidx];
            bool keep;
            compute_box((int)aidx, d, x0, y0, x1, y1, keep);
        }
    }
    bx0[r] = x0; by0[r] = y0; bx1[r] = x1; by1[r] = y1;
    bar[r] = (x1 - x0) * (y1 - y0);
}

// full IoU bitmask: (188 row-blocks x 4 col-quarters), LDS-staged column tiles
__global__ void k_mask(const float* __restrict__ bx0, const float* __restrict__ by0,
                       const float* __restrict__ bx1, const float* __restrict__ by1,
                       const float* __restrict__ bar, uint64_t* __restrict__ mask)
{
    __shared__ float s0[256], s1[256], s2[256], s3[256], sa[256];
    int rr = threadIdx.x >> 2;
    int q  = threadIdx.x & 3;
    int r  = blockIdx.x * 64 + rr;
    int c0 = blockIdx.y * 12;
    int c1 = min(c0 + 12, NPAD / 256);   // 47 tiles total
    float rx0 = bx0[r], ry0 = by0[r], rx1 = bx1[r], ry1 = by1[r], ra = bar[r];
    for (int c = c0; c < c1; ++c) {
        int cb = c * 256;
        __syncthreads();
        int t = threadIdx.x;
        s0[t] = bx0[cb + t]; s1[t] = by0[cb + t];
        s2[t] = bx1[cb + t]; s3[t] = by1[cb + t];
        sa[t] = bar[cb + t];
        __syncthreads();
        uint64_t bits = 0;
        int j0 = q * 64;
        #pragma unroll 4
        for (int j = 0; j < 64; ++j) {
            int jj = j0 + j;
            float ix0 = fmaxf(rx0, s0[jj]);
            float iy0 = fmaxf(ry0, s1[jj]);
            float ix1 = fminf(rx1, s2[jj]);
            float iy1 = fminf(ry1, s3[jj]);
            float iw = fmaxf(ix1 - ix0, 0.f);
            float ih = fmaxf(iy1 - iy0, 0.f);
            float inter = iw * ih;
            float denom = ra + sa[jj] - inter + 1e-9f;   // ((ra+sa)-inter)+eps, as ref
            float iou = inter / denom;
            bits |= ((uint64_t)(iou > 0.7f)) << j;
        }
        mask[(size_t)r * WORDS + (size_t)(c * 4 + q)] = bits;
    }
}

// serial greedy NMS, pipelined: per-word critical path is ALU-only.
// For word iw we hold (prefetched one iteration ahead):
//   Dcur[lane] = mask[iw*64+lane][iw]    (diagonal block)
//   Dnxt[lane] = mask[iw*64+lane][iw+1]  (next-word column of candidates)
// Select loop updates avail via Dcur shfl and accumulates nextOr via Dnxt shfl.
// Full-row loads (words >= iw+2 only) are issued as PENDING and OR-committed
// one iteration later, hiding their latency under the next word's select loop.
__global__ __launch_bounds__(64, 1)
void k_nms(const uint64_t* __restrict__ mask, int* __restrict__ sel,
           uint32_t* __restrict__ state)
{
    const int lane = threadIdx.x;     // blockDim = 64 (one wave)
    uint64_t p0 = 0, p1 = 0, p2 = 0;  // lane owns words lane, 64+lane, 128+lane
    uint64_t q0[16], q1[16], q2[16];  // pending row loads (committed next iter)
    #pragma unroll
    for (int k = 0; k < 16; ++k) { q0[k] = 0; q1[k] = 0; q2[k] = 0; }
    int cnt = 0;
    const uint64_t* r0 = mask + (size_t)lane * WORDS;
    uint64_t Dcur = r0[0];
    uint64_t Dnxt = r0[1];
    uint64_t avail = ~0ull;           // word 0: nothing suppressed yet
    for (int iw = 0; iw < WORDS && cnt < KPOST; ++iw) {
        // prefetch diagonal pair for word iw+1 (independent of this word's work)
        uint64_t Pd = 0, Pn = 0;
        if (iw + 1 < WORDS) {
            const uint64_t* nr = mask + (size_t)((iw + 1) * 64 + lane) * WORDS;
            Pd = nr[iw + 1];
            Pn = (iw + 2 < WORDS) ? nr[iw + 2] : 0ull;
        }
        // serial select loop: pure ALU + shfl
        uint64_t selbits = 0, nextOr = 0;
        while (avail && cnt < KPOST) {
            int b = __ffsll((unsigned long long)avail) - 1;
            if (lane == 0) sel[cnt] = iw * 64 + b;
            ++cnt;
            selbits |= (1ull << b);
            avail &= ~(uint64_t)__shfl((unsigned long long)Dcur, b, 64);
            nextOr |= (uint64_t)__shfl((unsigned long long)Dnxt, b, 64);
        }
        // commit pending row loads from previous word (latency already hidden)
        #pragma unroll
        for (int k = 0; k < 16; ++k) { p0 |= q0[k]; p1 |= q1[k]; p2 |= q2[k]; }
        #pragma unroll
        for (int k = 0; k < 16; ++k) { q0[k] = 0; q1[k] = 0; q2[k] = 0; }
        // issue this word's full-row loads; only words >= iw+2 are ever read
        // again (word iw+1 is covered by nextOr)
        bool l0 = (lane       >= iw + 2);
        bool l1 = (64 + lane  >= iw + 2);
        bool l2 = (128 + lane >= iw + 2) && (lane < WORDS - 128);
        uint64_t sb = selbits;
        int ids[16];
        #pragma unroll
        for (int k = 0; k < 16; ++k) {
            ids[k] = sb ? (__ffsll((unsigned long long)sb) - 1) : -1;
            sb &= (sb - 1);
        }
        #pragma unroll
        for (int k = 0; k < 16; ++k) {
            if (ids[k] >= 0) {
                const uint64_t* row = mask + (size_t)(iw * 64 + ids[k]) * WORDS;
                if (l0) q0[k] = row[lane];
                if (l1) q1[k] = row[64 + lane];
                if (l2) q2[k] = row[128 + lane];
            }
        }
        // overflow (>16 picks in one word, rare): synchronous OR
        while (sb) {
            int b = __ffsll((unsigned long long)sb) - 1;
            sb &= (sb - 1);
            const uint64_t* row = mask + (size_t)(iw * 64 + b) * WORDS;
            if (l0) p0 |= row[lane];
            if (l1) p1 |= row[64 + lane];
            if (l2) p2 |= row[128 + lane];
        }
        // avail for word iw+1: p (selections <= iw-1) | nextOr (this word)
        if (iw + 1 < WORDS) {
            int w = iw + 1;
            int slot = w >> 6;
            uint64_t pv = (slot == 0) ? p0 : ((slot == 1) ? p1 : p2);
            uint64_t pword = (uint64_t)__shfl((unsigned long long)pv, w & 63, 64);
            uint64_t validm = (w == WORDS - 1) ? 0xFFFFFFFFull : ~0ull;
            avail = (~(pword | nextOr)) & validm;
        }
        Dcur = Pd;
        Dnxt = Pn;
    }
    if (lane == 0) state[6] = (uint32_t)cnt;
}

__global__ void k_gather(const float* __restrict__ bx0, const float* __restrict__ by0,
                         const float* __restrict__ bx1, const float* __restrict__ by1,
                         const int* __restrict__ sel, const uint32_t* __restrict__ state,
                         float4* __restrict__ out)
{
    int slot = blockIdx.x * blockDim.x + threadIdx.x;
    if (slot >= KPOST) return;
    uint32_t cnt = state[6];
    float4 v = make_float4(0.f, 0.f, 0.f, 0.f);
    if ((uint32_t)slot < cnt) {
        int i = sel[slot];
        v = make_float4(bx0[i], by0[i], bx1[i], by1[i]);
    }
    out[slot] = v;
}

extern "C" void kernel_launch(void* const* d_in, const int* in_sizes, int n_in,
                              void* d_out, int out_size, void* d_ws, size_t ws_size,
                              hipStream_t stream)
{
    const float* delta = (const float*)d_in[0];
    const float* score = (const float*)d_in[1];
    float4* out = (float4*)d_out;

    uint8_t* p = (uint8_t*)d_ws;
    auto alloc = [&](size_t bytes) -> void* {
        void* r = (void*)p;
        p += (bytes + 255) & ~(size_t)255;
        return r;
    };
    uint32_t* keys          = (uint32_t*)alloc((size_t)N_TOTAL * 4);
    uint32_t* hist1         = (uint32_t*)alloc(2048 * 4);
    uint32_t* hist2         = (uint32_t*)alloc(2048 * 4);
    uint32_t* hist3         = (uint32_t*)alloc(1024 * 4);
    uint32_t* state         = (uint32_t*)alloc(64);
    uint64_t* cand          = (uint64_t*)alloc((size_t)CAND_CAP * 8);
    uint32_t* sorted_anchor = (uint32_t*)alloc((size_t)NPAD * 4);
    float*    bx0           = (float*)alloc((size_t)NPAD * 4);
    float*    by0           = (float*)alloc((size_t)NPAD * 4);
    float*    bx1           = (float*)alloc((size_t)NPAD * 4);
    float*    by1           = (float*)alloc((size_t)NPAD * 4);
    float*    bar           = (float*)alloc((size_t)NPAD * 4);
    int*      sel           = (int*)alloc((size_t)KPOST * 4);
    uint64_t* mask          = (uint64_t*)alloc((size_t)NPAD * WORDS * 8);
    (void)ws_size; (void)n_in; (void)in_sizes; (void)out_size;

    const int B = 256;
    const int gN = (N_TOTAL + B - 1) / B;

    hipLaunchKernelGGL(k_init, dim3(68), dim3(B), 0, stream,
                       hist1, hist2, hist3, state, sorted_anchor);
    hipLaunchKernelGGL(k_keys, dim3(gN), dim3(B), 0, stream, delta, score, keys, hist1);
    hipLaunchKernelGGL(k_scan, dim3(1), dim3(B), 0, stream, hist1, state, 2048, 0);
    hipLaunchKernelGGL(k_hist2, dim3(gN), dim3(B), 0, stream, keys, state, hist2);
    hipLaunchKernelGGL(k_scan, dim3(1), dim3(B), 0, stream, hist2, state, 2048, 1);
    hipLaunchKernelGGL(k_hist3, dim3(gN), dim3(B), 0, stream, keys, state, hist3);
    hipLaunchKernelGGL(k_scan, dim3(1), dim3(B), 0, stream, hist3, state, 1024, 2);
    hipLaunchKernelGGL(k_compact, dim3(gN), dim3(B), 0, stream, keys, state, cand);
    hipLaunchKernelGGL(k_ranksort, dim3(CAND_CAP / B), dim3(B), 0, stream,
                       cand, state, sorted_anchor);
    hipLaunchKernelGGL(k_boxes, dim3(NPAD / B), dim3(B), 0, stream,
                       delta, sorted_anchor, bx0, by0, bx1, by1, bar);
    hipLaunchKernelGGL(k_mask, dim3(NPAD / 64, 4), dim3(B), 0, stream,
                       bx0, by0, bx1, by1, bar, mask);
    hipLaunchKernelGGL(k_nms, dim3(1), dim3(64), 0, stream, mask, sel, state);
    hipLaunchKernelGGL(k_gather, dim3((KPOST + B - 1) / B), dim3(B), 0, stream,
                       bx0, by0, bx1, by1, sel, state, out);
}

// Round 4
// 1210.638 us; speedup vs baseline: 1.6831x; 1.6831x over previous
//
#include <hip/hip_runtime.h>
#include <stdint.h>

#define N_TOTAL  1327104     // 384*384*9
#define KPRE     12000
#define KPOST    2000
#define NPAD     12032       // KPRE padded to 64
#define WORDS    188         // 12032/64
#define CAND_CAP 16384
#define IMGLIM   6144.0f

// 9 base anchors (ratio-major, scale-minor). All centered at (7.5,7.5) so
// cx = col*16 + 8, cy = row*16 + 8 exactly; only (w,h) vary per anchor.
__constant__ float c_aw[9] = {184.f,368.f,736.f,128.f,256.f,512.f, 88.f,176.f,352.f};
__constant__ float c_ah[9] = { 96.f,192.f,384.f,128.f,256.f,512.f,176.f,352.f,704.f};

// block FMA contraction: numpy computes d*w (round) then +c (round)
__device__ __forceinline__ float mul_sep(float a, float b) {
    float r = a * b;
    asm volatile("" : "+v"(r));
    return r;
}

__device__ __forceinline__ void compute_box(int idx, const float4 d,
        float& ox0, float& oy0, float& ox1, float& oy1, bool& keep)
{
    int a    = idx % 9;
    int cell = idx / 9;
    int col  = cell % 384;
    int row  = cell / 384;
    float w = c_aw[a], h = c_ah[a];
    float cx = (float)(col * 16 + 8);
    float cy = (float)(row * 16 + 8);
    float pcx = mul_sep(d.x, w) + cx;
    float pcy = mul_sep(d.y, h) + cy;
    float pw = expf(d.z) * w;
    float ph = expf(d.w) * h;
    // 0.5f*pw is exact halving -> contraction-safe
    float x0 = pcx - 0.5f * pw;
    float y0 = pcy - 0.5f * ph;
    float x1 = pcx + 0.5f * pw;
    float y1 = pcy + 0.5f * ph;
    ox0 = fminf(fmaxf(x0, 0.f), IMGLIM);
    oy0 = fminf(fmaxf(y0, 0.f), IMGLIM);
    ox1 = fminf(fmaxf(x1, 0.f), IMGLIM);
    oy1 = fminf(fmaxf(y1, 0.f), IMGLIM);
    keep = ((ox1 - ox0) >= 16.f) && ((oy1 - oy0) >= 16.f);
}

__global__ void k_init(uint32_t* hist1, uint32_t* hist2, uint32_t* hist3,
                       uint32_t* state, uint32_t* sorted_anchor)
{
    int t = blockIdx.x * blockDim.x + threadIdx.x;
    if      (t < 2048) hist1[t] = 0;
    else if (t < 4096) hist2[t - 2048] = 0;
    else if (t < 5120) hist3[t - 4096] = 0;
    else if (t < 5136) state[t - 5120] = 0;
    int u = t - 5136;
    if (u >= 0 && u < NPAD) sorted_anchor[u] = 0xFFFFFFFFu;
}

// keys: score bits if box passes min-size filter else 0; + pass-1 histogram (top 11 bits)
__global__ void k_keys(const float* __restrict__ delta, const float* __restrict__ score,
                       uint32_t* __restrict__ keys, uint32_t* __restrict__ hist1)
{
    __shared__ uint32_t lh[2048];
    for (int t = threadIdx.x; t < 2048; t += blockDim.x) lh[t] = 0;
    __syncthreads();
    int idx = blockIdx.x * blockDim.x + threadIdx.x;
    if (idx < N_TOTAL) {
        float4 d = ((const float4*)delta)[idx];
        float x0, y0, x1, y1; bool keep;
        compute_box(idx, d, x0, y0, x1, y1, keep);
        float s = ((const float2*)score)[idx].y;
        uint32_t key = keep ? __float_as_uint(s) : 0u;   // s in [0,1): bits monotonic
        keys[idx] = key;
        atomicAdd(&lh[key >> 21], 1u);
    }
    __syncthreads();
    for (int t = threadIdx.x; t < 2048; t += blockDim.x) {
        uint32_t c = lh[t];
        if (c) atomicAdd(&hist1[t], c);
    }
}

__global__ void k_hist2(const uint32_t* __restrict__ keys, const uint32_t* __restrict__ state,
                        uint32_t* __restrict__ hist)
{
    __shared__ uint32_t lh[2048];
    for (int t = threadIdx.x; t < 2048; t += blockDim.x) lh[t] = 0;
    __syncthreads();
    uint32_t B1 = state[0];
    int idx = blockIdx.x * blockDim.x + threadIdx.x;
    if (idx < N_TOTAL) {
        uint32_t k = keys[idx];
        if ((k >> 21) == B1) atomicAdd(&lh[(k >> 10) & 0x7FFu], 1u);
    }
    __syncthreads();
    for (int t = threadIdx.x; t < 2048; t += blockDim.x) {
        uint32_t c = lh[t];
        if (c) atomicAdd(&hist[t], c);
    }
}

__global__ void k_hist3(const uint32_t* __restrict__ keys, const uint32_t* __restrict__ state,
                        uint32_t* __restrict__ hist)
{
    __shared__ uint32_t lh[1024];
    for (int t = threadIdx.x; t < 1024; t += blockDim.x) lh[t] = 0;
    __syncthreads();
    uint32_t pfx = state[2];
    int idx = blockIdx.x * blockDim.x + threadIdx.x;
    if (idx < N_TOTAL) {
        uint32_t k = keys[idx];
        if ((k >> 10) == pfx) atomicAdd(&lh[k & 0x3FFu], 1u);
    }
    __syncthreads();
    for (int t = threadIdx.x; t < 1024; t += blockDim.x) {
        uint32_t c = lh[t];
        if (c) atomicAdd(&hist[t], c);
    }
}

// find bin containing the K-th largest: parallel suffix-scan over bins
__global__ void k_scan(const uint32_t* __restrict__ hist, uint32_t* __restrict__ state,
                       int nbins, int pass)
{
    __shared__ uint32_t sh[2048];
    __shared__ uint32_t part[256];
    __shared__ uint32_t sB, sRem;
    int t = threadIdx.x;                 // 256 threads
    int seg = nbins >> 8;                // 8 or 4
    uint32_t K = (pass == 0) ? (uint32_t)KPRE : ((pass == 1) ? state[1] : state[3]);
    if (K == 0u) K = 1u;
    uint32_t local = 0;
    for (int i = 0; i < seg; ++i) {
        uint32_t h = hist[t * seg + i];
        sh[t * seg + i] = h;
        local += h;
    }
    part[t] = local;
    __syncthreads();
    // inclusive suffix sum over part[]
    for (int off = 1; off < 256; off <<= 1) {
        uint32_t v = part[t];
        uint32_t add = (t + off < 256) ? part[t + off] : 0u;
        __syncthreads();
        part[t] = v + add;
        __syncthreads();
    }
    uint32_t mine  = part[t];                         // sum of bins >= t*seg
    uint32_t below = (t + 1 < 256) ? part[t + 1] : 0; // sum of bins >= (t+1)*seg
    if (mine >= K && below < K) {                     // unique thread
        uint32_t cum = below;
        for (int i = seg - 1; i >= 0; --i) {
            uint32_t h = sh[t * seg + i];
            if (cum + h >= K) { sB = (uint32_t)(t * seg + i); sRem = K - cum; break; }
            cum += h;
        }
    }
    __syncthreads();
    if (t == 0) {
        uint32_t B = sB, rem = sRem;
        if      (pass == 0) { state[0] = B; state[1] = rem; }
        else if (pass == 1) { state[2] = (state[0] << 11) | B; state[3] = rem; }
        else                { state[4] = (state[2] << 10) | B; }
    }
}

// compact all keys >= threshold; wave-aggregated atomic (1 per active wave)
__global__ void k_compact(const uint32_t* __restrict__ keys, uint32_t* __restrict__ state,
                          uint64_t* __restrict__ cand)
{
    uint32_t T = state[4];
    int idx = blockIdx.x * blockDim.x + threadIdx.x;
    bool pred = false; uint32_t k = 0;
    if (idx < N_TOTAL) { k = keys[idx]; pred = (k >= T); }
    uint64_t bal = __ballot(pred);
    if (bal == 0ull) return;
    int lane = threadIdx.x & 63;
    int leader = __ffsll((unsigned long long)bal) - 1;
    uint32_t base = 0;
    if (lane == leader) base = atomicAdd(&state[5], (uint32_t)__popcll((unsigned long long)bal));
    base = (uint32_t)__shfl((int)base, leader, 64);
    if (pred) {
        uint64_t lower = (lane == 0) ? 0ull : (~0ull >> (64 - lane));
        uint32_t p = base + (uint32_t)__popcll((unsigned long long)(bal & lower));
        if (p < CAND_CAP)
            cand[p] = ((uint64_t)k << 32) | (uint64_t)(0xFFFFFFFFu - (uint32_t)idx);
    }
}

// exact rank sort: rank = #{j : key_j > key_i}; keys unique -> bijective
__global__ void k_ranksort(const uint64_t* __restrict__ cand, const uint32_t* __restrict__ state,
                           uint32_t* __restrict__ sorted_anchor)
{
    __shared__ uint64_t lk[2048];
    uint32_t M = min(state[5], (uint32_t)CAND_CAP);
    int i = blockIdx.x * blockDim.x + threadIdx.x;
    uint64_t mykey = (i < (int)M) ? cand[i] : 0ull;
    uint32_t rank = 0;
    for (uint32_t base = 0; base < M; base += 2048) {
        uint32_t chunk = min(2048u, M - base);
        __syncthreads();
        for (uint32_t t = threadIdx.x; t < chunk; t += blockDim.x) lk[t] = cand[base + t];
        __syncthreads();
        if (i < (int)M)
            for (uint32_t j = 0; j < chunk; ++j) rank += (lk[j] > mykey) ? 1u : 0u;
    }
    if (i < (int)M && rank < KPRE)
        sorted_anchor[rank] = 0xFFFFFFFFu - (uint32_t)(mykey & 0xFFFFFFFFull);
}

__global__ void k_boxes(const float* __restrict__ delta, const uint32_t* __restrict__ sorted_anchor,
                        float* __restrict__ bx0, float* __restrict__ by0,
                        float* __restrict__ bx1, float* __restrict__ by1,
                        float* __restrict__ bar)
{
    int r = blockIdx.x * blockDim.x + threadIdx.x;
    if (r >= NPAD) return;
    float x0 = 0.f, y0 = 0.f, x1 = 0.f, y1 = 0.f;
    if (r < KPRE) {
        uint32_t aidx = sorted_anchor[r];
        if (aidx < (uint32_t)N_TOTAL) {
            float4 d = ((const float4*)delta)[aidx];
            bool keep;
            compute_box((int)aidx, d, x0, y0, x1, y1, keep);
        }
    }
    bx0[r] = x0; by0[r] = y0; bx1[r] = x1; by1[r] = y1;
    bar[r] = (x1 - x0) * (y1 - y0);
}

// full IoU bitmask: (188 row-blocks x 4 col-quarters), LDS-staged column tiles.
// Also emits coalesced diagonal bands for k_nms staging:
//   diagband[iw*64+l] = mask[iw*64+l][iw], nextband[iw*64+l] = mask[iw*64+l][iw+1]
__global__ void k_mask(const float* __restrict__ bx0, const float* __restrict__ by0,
                       const float* __restrict__ bx1, const float* __restrict__ by1,
                       const float* __restrict__ bar, uint64_t* __restrict__ mask,
                       uint64_t* __restrict__ diagband, uint64_t* __restrict__ nextband)
{
    __shared__ float s0[256], s1[256], s2[256], s3[256], sa[256];
    int rr = threadIdx.x >> 2;
    int q  = threadIdx.x & 3;
    int bx = blockIdx.x;
    int r  = bx * 64 + rr;
    int c0 = blockIdx.y * 12;
    int c1 = min(c0 + 12, NPAD / 256);   // 47 tiles total
    float rx0 = bx0[r], ry0 = by0[r], rx1 = bx1[r], ry1 = by1[r], ra = bar[r];
    for (int c = c0; c < c1; ++c) {
        int cb = c * 256;
        __syncthreads();
        int t = threadIdx.x;
        s0[t] = bx0[cb + t]; s1[t] = by0[cb + t];
        s2[t] = bx1[cb + t]; s3[t] = by1[cb + t];
        sa[t] = bar[cb + t];
        __syncthreads();
        uint64_t bits = 0;
        int j0 = q * 64;
        #pragma unroll 4
        for (int j = 0; j < 64; ++j) {
            int jj = j0 + j;
            float ix0 = fmaxf(rx0, s0[jj]);
            float iy0 = fmaxf(ry0, s1[jj]);
            float ix1 = fminf(rx1, s2[jj]);
            float iy1 = fminf(ry1, s3[jj]);
            float iw = fmaxf(ix1 - ix0, 0.f);
            float ih = fmaxf(iy1 - iy0, 0.f);
            float inter = iw * ih;
            float denom = ra + sa[jj] - inter + 1e-9f;   // ((ra+sa)-inter)+eps, as ref
            float iou = inter / denom;
            bits |= ((uint64_t)(iou > 0.7f)) << j;
        }
        int w = c * 4 + q;
        mask[(size_t)r * WORDS + (size_t)w] = bits;
        if (w == bx)          diagband[bx * 64 + rr] = bits;
        else if (w == bx + 1) nextband[bx * 64 + rr] = bits;
    }
}

// Cooperative greedy NMS: 16 waves. Wave 0 = selector (ALU-only critical path,
// diag/nextcol staged in double-buffered LDS). Waves 1-15 = workers: OR the
// previous word's selected rows into the LDS suppression mask (coalesced,
// 32-bit LDS atomics) and prefetch the next word's bands.
// Invariant at wave0's avail(iw+1) computation (after barrier B):
//   p_lds[iw+1] = OR of rows picked in words <= iw-1  (workers, this iter)
//   nextOr      = OR of word-(iw+1) bits of picks(iw) (selector, via nextband)
__global__ __launch_bounds__(1024, 1)
void k_nms(const uint64_t* __restrict__ mask, const uint64_t* __restrict__ diagband,
           const uint64_t* __restrict__ nextband, int* __restrict__ sel,
           uint32_t* __restrict__ state)
{
    __shared__ uint32_t p32[WORDS * 2];     // suppression mask, 32-bit halves
    __shared__ uint64_t diag0[64], diag1[64], next0[64], next1[64];
    __shared__ uint64_t selbS;
    __shared__ uint32_t stopF;
    const int tid  = threadIdx.x;
    const int lane = tid & 63;
    const int wtid = tid - 64;              // worker index 0..959

    // init
    if (tid < WORDS * 2) p32[tid] = 0;
    if (tid == 0) { selbS = 0ull; stopF = 0u; }
    if (wtid >= 0 && wtid < 64)       diag0[wtid] = diagband[wtid];
    else if (wtid >= 64 && wtid < 128) next0[wtid - 64] = nextband[wtid - 64];
    __syncthreads();

    uint64_t avail = ~0ull;                 // word 0: nothing suppressed
    int cnt = 0;                            // wave0 lanes, lockstep
    for (int iw = 0; iw < WORDS; ++iw) {
        uint64_t nextOr = 0, selbits = 0;
        int cnt0 = cnt;
        if (tid < 64) {
            // ---- selector ----
            uint64_t Dc = (iw & 1) ? diag1[lane] : diag0[lane];
            uint64_t Dn = (iw & 1) ? next1[lane] : next0[lane];
            while (avail && cnt < KPOST) {
                int b = __ffsll((unsigned long long)avail) - 1;
                selbits |= (1ull << b);
                ++cnt;
                avail &= ~(uint64_t)__shfl((unsigned long long)Dc, b, 64);
                nextOr |= (uint64_t)__shfl((unsigned long long)Dn, b, 64);
            }
            // parallel store of this word's picks (lane j stores j-th pick)
            int npick = cnt - cnt0;
            if (lane < npick) {
                uint64_t s = selbits;
                for (int q = 0; q < lane; ++q) s &= s - 1;
                sel[cnt0 + lane] = iw * 64 + (__ffsll((unsigned long long)s) - 1);
            }
        } else {
            // ---- workers ----
            uint64_t sb = selbS;            // picks of word iw-1
            // prefetch bands for word iw+1 into the other buffer
            if (iw + 1 < WORDS) {
                if (wtid < 64) {
                    uint64_t v = diagband[(iw + 1) * 64 + wtid];
                    if (iw & 1) diag0[wtid] = v; else diag1[wtid] = v;
                } else if (wtid < 128) {
                    int l = wtid - 64;
                    uint64_t v = (iw + 2 < WORDS) ? nextband[(iw + 1) * 64 + l] : 0ull;
                    if (iw & 1) next0[l] = v; else next1[l] = v;
                }
            }
            // OR full rows of picks(iw-1) into p_lds
            if (iw > 0 && sb) {
                int nsel = __popcll((unsigned long long)sb);
                int total = nsel * WORDS;
                int rowbase = (iw - 1) * 64;
                for (int e = wtid; e < total; e += 960) {
                    int j = e / WORDS;
                    int w = e - j * WORDS;
                    uint64_t s = sb;
                    for (int q = 0; q < j; ++q) s &= s - 1;
                    int r = __ffsll((unsigned long long)s) - 1;
                    uint64_t v = mask[(size_t)(rowbase + r) * WORDS + w];
                    if (v) {
                        uint32_t lo = (uint32_t)v, hi = (uint32_t)(v >> 32);
                        if (lo) atomicOr(&p32[2 * w], lo);
                        if (hi) atomicOr(&p32[2 * w + 1], hi);
                    }
                }
            }
        }
        __syncthreads();    // barrier B: p_lds[iw+1] final for rows <= iw-1
        if (tid < 64) {
            if (iw + 1 < WORDS) {
                uint64_t pw = ((uint64_t)p32[2 * (iw + 1) + 1] << 32) | (uint64_t)p32[2 * (iw + 1)];
                uint64_t validm = (iw + 1 == WORDS - 1) ? 0xFFFFFFFFull : ~0ull;
                avail = (~(pw | nextOr)) & validm;
            }
            if (lane == 0) {
                selbS = selbits;
                if (cnt >= KPOST || iw + 1 >= WORDS) stopF = 1u;
            }
        }
        __syncthreads();    // barrier A: selbS/stopF published, bufs staged
        if (stopF) break;
    }
    if (tid == 0) state[6] = (uint32_t)cnt;
}

__global__ void k_gather(const float* __restrict__ bx0, const float* __restrict__ by0,
                         const float* __restrict__ bx1, const float* __restrict__ by1,
                         const int* __restrict__ sel, const uint32_t* __restrict__ state,
                         float4* __restrict__ out)
{
    int slot = blockIdx.x * blockDim.x + threadIdx.x;
    if (slot >= KPOST) return;
    uint32_t cnt = state[6];
    float4 v = make_float4(0.f, 0.f, 0.f, 0.f);
    if ((uint32_t)slot < cnt) {
        int i = sel[slot];
        v = make_float4(bx0[i], by0[i], bx1[i], by1[i]);
    }
    out[slot] = v;
}

extern "C" void kernel_launch(void* const* d_in, const int* in_sizes, int n_in,
                              void* d_out, int out_size, void* d_ws, size_t ws_size,
                              hipStream_t stream)
{
    const float* delta = (const float*)d_in[0];
    const float* score = (const float*)d_in[1];
    float4* out = (float4*)d_out;

    uint8_t* p = (uint8_t*)d_ws;
    auto alloc = [&](size_t bytes) -> void* {
        void* r = (void*)p;
        p += (bytes + 255) & ~(size_t)255;
        return r;
    };
    uint32_t* keys          = (uint32_t*)alloc((size_t)N_TOTAL * 4);
    uint32_t* hist1         = (uint32_t*)alloc(2048 * 4);
    uint32_t* hist2         = (uint32_t*)alloc(2048 * 4);
    uint32_t* hist3         = (uint32_t*)alloc(1024 * 4);
    uint32_t* state         = (uint32_t*)alloc(64);
    uint64_t* cand          = (uint64_t*)alloc((size_t)CAND_CAP * 8);
    uint32_t* sorted_anchor = (uint32_t*)alloc((size_t)NPAD * 4);
    float*    bx0           = (float*)alloc((size_t)NPAD * 4);
    float*    by0           = (float*)alloc((size_t)NPAD * 4);
    float*    bx1           = (float*)alloc((size_t)NPAD * 4);
    float*    by1           = (float*)alloc((size_t)NPAD * 4);
    float*    bar           = (float*)alloc((size_t)NPAD * 4);
    int*      sel           = (int*)alloc((size_t)KPOST * 4);
    uint64_t* diagband      = (uint64_t*)alloc((size_t)WORDS * 64 * 8);
    uint64_t* nextband      = (uint64_t*)alloc((size_t)WORDS * 64 * 8);
    uint64_t* mask          = (uint64_t*)alloc((size_t)NPAD * WORDS * 8);
    (void)ws_size; (void)n_in; (void)in_sizes; (void)out_size;

    const int B = 256;
    const int gN = (N_TOTAL + B - 1) / B;

    hipLaunchKernelGGL(k_init, dim3(68), dim3(B), 0, stream,
                       hist1, hist2, hist3, state, sorted_anchor);
    hipLaunchKernelGGL(k_keys, dim3(gN), dim3(B), 0, stream, delta, score, keys, hist1);
    hipLaunchKernelGGL(k_scan, dim3(1), dim3(B), 0, stream, hist1, state, 2048, 0);
    hipLaunchKernelGGL(k_hist2, dim3(gN), dim3(B), 0, stream, keys, state, hist2);
    hipLaunchKernelGGL(k_scan, dim3(1), dim3(B), 0, stream, hist2, state, 2048, 1);
    hipLaunchKernelGGL(k_hist3, dim3(gN), dim3(B), 0, stream, keys, state, hist3);
    hipLaunchKernelGGL(k_scan, dim3(1), dim3(B), 0, stream, hist3, state, 1024, 2);
    hipLaunchKernelGGL(k_compact, dim3(gN), dim3(B), 0, stream, keys, state, cand);
    hipLaunchKernelGGL(k_ranksort, dim3(CAND_CAP / B), dim3(B), 0, stream,
                       cand, state, sorted_anchor);
    hipLaunchKernelGGL(k_boxes, dim3(NPAD / B), dim3(B), 0, stream,
                       delta, sorted_anchor, bx0, by0, bx1, by1, bar);
    hipLaunchKernelGGL(k_mask, dim3(NPAD / 64, 4), dim3(B), 0, stream,
                       bx0, by0, bx1, by1, bar, mask, diagband, nextband);
    hipLaunchKernelGGL(k_nms, dim3(1), dim3(1024), 0, stream,
                       mask, diagband, nextband, sel, state);
    hipLaunchKernelGGL(k_gather, dim3((KPOST + B - 1) / B), dim3(B), 0, stream,
                       bx0, by0, bx1, by1, sel, state, out);
}

// Round 5
// 783.255 us; speedup vs baseline: 2.6015x; 1.5457x over previous
//
#include <hip/hip_runtime.h>
#include <stdint.h>

#define N_TOTAL  1327104     // 384*384*9
#define KPRE     12000
#define KPOST    2000
#define NPAD     12032       // KPRE padded to 64
#define WORDS    188         // 12032/64
#define CAND_CAP 16384
#define IMGLIM   6144.0f

// 9 base anchors (ratio-major, scale-minor). All centered at (7.5,7.5) so
// cx = col*16 + 8, cy = row*16 + 8 exactly; only (w,h) vary per anchor.
__constant__ float c_aw[9] = {184.f,368.f,736.f,128.f,256.f,512.f, 88.f,176.f,352.f};
__constant__ float c_ah[9] = { 96.f,192.f,384.f,128.f,256.f,512.f,176.f,352.f,704.f};

// block FMA contraction: numpy computes d*w (round) then +c (round)
__device__ __forceinline__ float mul_sep(float a, float b) {
    float r = a * b;
    asm volatile("" : "+v"(r));
    return r;
}

__device__ __forceinline__ void compute_box(int idx, const float4 d,
        float& ox0, float& oy0, float& ox1, float& oy1, bool& keep)
{
    int a    = idx % 9;
    int cell = idx / 9;
    int col  = cell % 384;
    int row  = cell / 384;
    float w = c_aw[a], h = c_ah[a];
    float cx = (float)(col * 16 + 8);
    float cy = (float)(row * 16 + 8);
    float pcx = mul_sep(d.x, w) + cx;
    float pcy = mul_sep(d.y, h) + cy;
    float pw = expf(d.z) * w;
    float ph = expf(d.w) * h;
    // 0.5f*pw is exact halving -> contraction-safe
    float x0 = pcx - 0.5f * pw;
    float y0 = pcy - 0.5f * ph;
    float x1 = pcx + 0.5f * pw;
    float y1 = pcy + 0.5f * ph;
    ox0 = fminf(fmaxf(x0, 0.f), IMGLIM);
    oy0 = fminf(fmaxf(y0, 0.f), IMGLIM);
    ox1 = fminf(fmaxf(x1, 0.f), IMGLIM);
    oy1 = fminf(fmaxf(y1, 0.f), IMGLIM);
    keep = ((ox1 - ox0) >= 16.f) && ((oy1 - oy0) >= 16.f);
}

__global__ void k_init(uint32_t* hist1, uint32_t* hist2, uint32_t* hist3,
                       uint32_t* state, uint32_t* sorted_anchor,
                       uint64_t* band1, uint64_t* band2)
{
    int t = blockIdx.x * blockDim.x + threadIdx.x;
    if      (t < 2048) hist1[t] = 0;
    else if (t < 4096) hist2[t - 2048] = 0;
    else if (t < 5120) hist3[t - 4096] = 0;
    else if (t < 5136) state[t - 5120] = 0;
    else if (t < 5136 + NPAD) sorted_anchor[t - 5136] = 0xFFFFFFFFu;
    else if (t < 5136 + NPAD + 64)  band1[t - 5136 - NPAD] = 0ull;       // word 0 rows
    else if (t < 5136 + NPAD + 192) band2[t - 5136 - NPAD - 64] = 0ull;  // word 0-1 rows
}

// keys: score bits if box passes min-size filter else 0; + pass-1 histogram (top 11 bits)
__global__ void k_keys(const float* __restrict__ delta, const float* __restrict__ score,
                       uint32_t* __restrict__ keys, uint32_t* __restrict__ hist1)
{
    __shared__ uint32_t lh[2048];
    for (int t = threadIdx.x; t < 2048; t += blockDim.x) lh[t] = 0;
    __syncthreads();
    int idx = blockIdx.x * blockDim.x + threadIdx.x;
    if (idx < N_TOTAL) {
        float4 d = ((const float4*)delta)[idx];
        float x0, y0, x1, y1; bool keep;
        compute_box(idx, d, x0, y0, x1, y1, keep);
        float s = ((const float2*)score)[idx].y;
        uint32_t key = keep ? __float_as_uint(s) : 0u;   // s in [0,1): bits monotonic
        keys[idx] = key;
        atomicAdd(&lh[key >> 21], 1u);
    }
    __syncthreads();
    for (int t = threadIdx.x; t < 2048; t += blockDim.x) {
        uint32_t c = lh[t];
        if (c) atomicAdd(&hist1[t], c);
    }
}

__global__ void k_hist2(const uint32_t* __restrict__ keys, const uint32_t* __restrict__ state,
                        uint32_t* __restrict__ hist)
{
    __shared__ uint32_t lh[2048];
    for (int t = threadIdx.x; t < 2048; t += blockDim.x) lh[t] = 0;
    __syncthreads();
    uint32_t B1 = state[0];
    int idx = blockIdx.x * blockDim.x + threadIdx.x;
    if (idx < N_TOTAL) {
        uint32_t k = keys[idx];
        if ((k >> 21) == B1) atomicAdd(&lh[(k >> 10) & 0x7FFu], 1u);
    }
    __syncthreads();
    for (int t = threadIdx.x; t < 2048; t += blockDim.x) {
        uint32_t c = lh[t];
        if (c) atomicAdd(&hist[t], c);
    }
}

__global__ void k_hist3(const uint32_t* __restrict__ keys, const uint32_t* __restrict__ state,
                        uint32_t* __restrict__ hist)
{
    __shared__ uint32_t lh[1024];
    for (int t = threadIdx.x; t < 1024; t += blockDim.x) lh[t] = 0;
    __syncthreads();
    uint32_t pfx = state[2];
    int idx = blockIdx.x * blockDim.x + threadIdx.x;
    if (idx < N_TOTAL) {
        uint32_t k = keys[idx];
        if ((k >> 10) == pfx) atomicAdd(&lh[k & 0x3FFu], 1u);
    }
    __syncthreads();
    for (int t = threadIdx.x; t < 1024; t += blockDim.x) {
        uint32_t c = lh[t];
        if (c) atomicAdd(&hist[t], c);
    }
}

// find bin containing the K-th largest: parallel suffix-scan over bins
__global__ void k_scan(const uint32_t* __restrict__ hist, uint32_t* __restrict__ state,
                       int nbins, int pass)
{
    __shared__ uint32_t sh[2048];
    __shared__ uint32_t part[256];
    __shared__ uint32_t sB, sRem;
    int t = threadIdx.x;                 // 256 threads
    int seg = nbins >> 8;                // 8 or 4
    uint32_t K = (pass == 0) ? (uint32_t)KPRE : ((pass == 1) ? state[1] : state[3]);
    if (K == 0u) K = 1u;
    uint32_t local = 0;
    for (int i = 0; i < seg; ++i) {
        uint32_t h = hist[t * seg + i];
        sh[t * seg + i] = h;
        local += h;
    }
    part[t] = local;
    __syncthreads();
    // inclusive suffix sum over part[]
    for (int off = 1; off < 256; off <<= 1) {
        uint32_t v = part[t];
        uint32_t add = (t + off < 256) ? part[t + off] : 0u;
        __syncthreads();
        part[t] = v + add;
        __syncthreads();
    }
    uint32_t mine  = part[t];                         // sum of bins >= t*seg
    uint32_t below = (t + 1 < 256) ? part[t + 1] : 0; // sum of bins >= (t+1)*seg
    if (mine >= K && below < K) {                     // unique thread
        uint32_t cum = below;
        for (int i = seg - 1; i >= 0; --i) {
            uint32_t h = sh[t * seg + i];
            if (cum + h >= K) { sB = (uint32_t)(t * seg + i); sRem = K - cum; break; }
            cum += h;
        }
    }
    __syncthreads();
    if (t == 0) {
        uint32_t B = sB, rem = sRem;
        if      (pass == 0) { state[0] = B; state[1] = rem; }
        else if (pass == 1) { state[2] = (state[0] << 11) | B; state[3] = rem; }
        else                { state[4] = (state[2] << 10) | B; }
    }
}

// compact all keys >= threshold; wave-aggregated atomic (1 per active wave)
__global__ void k_compact(const uint32_t* __restrict__ keys, uint32_t* __restrict__ state,
                          uint64_t* __restrict__ cand)
{
    uint32_t T = state[4];
    int idx = blockIdx.x * blockDim.x + threadIdx.x;
    bool pred = false; uint32_t k = 0;
    if (idx < N_TOTAL) { k = keys[idx]; pred = (k >= T); }
    uint64_t bal = __ballot(pred);
    if (bal == 0ull) return;
    int lane = threadIdx.x & 63;
    int leader = __ffsll((unsigned long long)bal) - 1;
    uint32_t base = 0;
    if (lane == leader) base = atomicAdd(&state[5], (uint32_t)__popcll((unsigned long long)bal));
    base = (uint32_t)__shfl((int)base, leader, 64);
    if (pred) {
        uint64_t lower = (lane == 0) ? 0ull : (~0ull >> (64 - lane));
        uint32_t p = base + (uint32_t)__popcll((unsigned long long)(bal & lower));
        if (p < CAND_CAP)
            cand[p] = ((uint64_t)k << 32) | (uint64_t)(0xFFFFFFFFu - (uint32_t)idx);
    }
}

// exact rank sort: rank = #{j : key_j > key_i}; keys unique -> bijective
__global__ void k_ranksort(const uint64_t* __restrict__ cand, const uint32_t* __restrict__ state,
                           uint32_t* __restrict__ sorted_anchor)
{
    __shared__ uint64_t lk[2048];
    uint32_t M = min(state[5], (uint32_t)CAND_CAP);
    int i = blockIdx.x * blockDim.x + threadIdx.x;
    uint64_t mykey = (i < (int)M) ? cand[i] : 0ull;
    uint32_t rank = 0;
    for (uint32_t base = 0; base < M; base += 2048) {
        uint32_t chunk = min(2048u, M - base);
        __syncthreads();
        for (uint32_t t = threadIdx.x; t < chunk; t += blockDim.x) lk[t] = cand[base + t];
        __syncthreads();
        if (i < (int)M) {
            #pragma unroll 8
            for (uint32_t j = 0; j < chunk; ++j) rank += (lk[j] > mykey) ? 1u : 0u;
        }
    }
    if (i < (int)M && rank < KPRE)
        sorted_anchor[rank] = 0xFFFFFFFFu - (uint32_t)(mykey & 0xFFFFFFFFull);
}

__global__ void k_boxes(const float* __restrict__ delta, const uint32_t* __restrict__ sorted_anchor,
                        float* __restrict__ bx0, float* __restrict__ by0,
                        float* __restrict__ bx1, float* __restrict__ by1,
                        float* __restrict__ bar)
{
    int r = blockIdx.x * blockDim.x + threadIdx.x;
    if (r >= NPAD) return;
    float x0 = 0.f, y0 = 0.f, x1 = 0.f, y1 = 0.f;
    if (r < KPRE) {
        uint32_t aidx = sorted_anchor[r];
        if (aidx < (uint32_t)N_TOTAL) {
            float4 d = ((const float4*)delta)[aidx];
            bool keep;
            compute_box((int)aidx, d, x0, y0, x1, y1, keep);
        }
    }
    bx0[r] = x0; by0[r] = y0; bx1[r] = x1; by1[r] = y1;
    bar[r] = (x1 - x0) * (y1 - y0);
}

// full IoU bitmask: (188 row-blocks x 4 col-quarters), LDS-staged column tiles.
// Also emits coalesced bands for k_nms staging (word(r) = r/64):
//   diagband[r] = mask[r][word(r)]   band1[r] = mask[r][word(r)-1]
//   band2[r]    = mask[r][word(r)-2]
__global__ void k_mask(const float* __restrict__ bx0, const float* __restrict__ by0,
                       const float* __restrict__ bx1, const float* __restrict__ by1,
                       const float* __restrict__ bar, uint64_t* __restrict__ mask,
                       uint64_t* __restrict__ diagband, uint64_t* __restrict__ band1,
                       uint64_t* __restrict__ band2)
{
    __shared__ float s0[256], s1[256], s2[256], s3[256], sa[256];
    int rr = threadIdx.x >> 2;
    int q  = threadIdx.x & 3;
    int bx = blockIdx.x;
    int r  = bx * 64 + rr;
    int c0 = blockIdx.y * 12;
    int c1 = min(c0 + 12, NPAD / 256);   // 47 tiles total
    float rx0 = bx0[r], ry0 = by0[r], rx1 = bx1[r], ry1 = by1[r], ra = bar[r];
    for (int c = c0; c < c1; ++c) {
        int cb = c * 256;
        __syncthreads();
        int t = threadIdx.x;
        s0[t] = bx0[cb + t]; s1[t] = by0[cb + t];
        s2[t] = bx1[cb + t]; s3[t] = by1[cb + t];
        sa[t] = bar[cb + t];
        __syncthreads();
        uint64_t bits = 0;
        int j0 = q * 64;
        #pragma unroll 4
        for (int j = 0; j < 64; ++j) {
            int jj = j0 + j;
            float ix0 = fmaxf(rx0, s0[jj]);
            float iy0 = fmaxf(ry0, s1[jj]);
            float ix1 = fminf(rx1, s2[jj]);
            float iy1 = fminf(ry1, s3[jj]);
            float iw = fmaxf(ix1 - ix0, 0.f);
            float ih = fmaxf(iy1 - iy0, 0.f);
            float inter = iw * ih;
            float denom = ra + sa[jj] - inter + 1e-9f;   // ((ra+sa)-inter)+eps, as ref
            float iou = inter / denom;
            bits |= ((uint64_t)(iou > 0.7f)) << j;
        }
        int w = c * 4 + q;
        mask[(size_t)r * WORDS + (size_t)w] = bits;
        if      (w == bx)     diagband[r] = bits;
        else if (w == bx - 1) band1[r]    = bits;
        else if (w == bx - 2) band2[r]    = bits;
    }
}

// Cooperative greedy NMS v3. Uses IoU symmetry: a row's band segment equals
// the column segment, so all cross-lane data flow is via __ballot + SGPRs.
// Coverage of word w's availability (exact greedy order):
//   p32[w]           : picks <= w-3   (workers, deferred row-ORs)
//   band2[w] & pm2   : picks(w-2)     (selector registers)
//   band1[w] & pm1   : picks(w-1)
//   diag col shfl-free ballot loop: intra-word
// Workers ISSUE pick-row loads at iter q and COMMIT at iter q+1; barriers are
// raw s_barrier with lgkmcnt-only drain so the loads stay in flight (T4).
__global__ __launch_bounds__(1024, 1)
void k_nms(const uint64_t* __restrict__ mask, const uint64_t* __restrict__ diagband,
           const uint64_t* __restrict__ band1, const uint64_t* __restrict__ band2,
           int* __restrict__ sel, uint32_t* __restrict__ state)
{
    __shared__ uint32_t p32[WORDS * 2];        // suppression mask, 32-bit halves
    __shared__ uint64_t dbuf[2][64], b1buf[2][64], b2buf[2][64];
    __shared__ uint32_t pickrows[2][64];
    __shared__ uint32_t npickS[2];
    __shared__ uint32_t stopF;
    const int tid  = threadIdx.x;
    const int lane = tid & 63;
    const int wv   = tid >> 6;                 // 0 = selector, 1..15 = workers

    for (int t = tid; t < WORDS * 2; t += 1024) p32[t] = 0;
    if (tid == 0) { npickS[0] = 0; npickS[1] = 0; stopF = 0; }
    if (wv == 13) dbuf[0][lane]  = diagband[lane];
    if (wv == 14) b1buf[0][lane] = band1[lane];
    if (wv == 15) b2buf[0][lane] = band2[lane];
    __syncthreads();

    int cnt = 0;                               // selector-wave registers
    uint64_t pm1 = 0, pm2 = 0;
    uint64_t cv0 = 0, cv1 = 0, cv2 = 0;        // worker carry (values)
    int cw0 = WORDS, cw1 = WORDS, cw2 = WORDS; // worker carry (target words)

    for (int iw = 0; iw < WORDS; ++iw) {
        const int buf = iw & 1;
        if (wv == 0) {
            // ---------------- selector ----------------
            uint64_t col = dbuf[buf][lane];
            uint64_t pb1 = b1buf[buf][lane];
            uint64_t pb2 = b2buf[buf][lane];
            uint64_t pw  = ((uint64_t)p32[2 * iw + 1] << 32) | (uint64_t)p32[2 * iw];
            bool alive = !((pw >> lane) & 1) && !(pb1 & pm1) && !(pb2 & pm2);
            if (iw == WORDS - 1 && lane >= 32) alive = false;   // cols >= 12000 pad
            uint64_t pickmask = 0;
            int cnt0 = cnt;
            while (cnt < KPOST) {
                uint64_t bal = __ballot(alive);
                if (!bal) break;
                int b = __ffsll((unsigned long long)bal) - 1;
                pickmask |= (1ull << b);
                ++cnt;
                alive = alive && !((col >> b) & 1);  // self-bit set -> b dies
            }
            int np = cnt - cnt0;
            if (lane < np) {
                uint64_t s = pickmask;
                for (int q = 0; q < lane; ++q) s &= s - 1;
                int b = __ffsll((unsigned long long)s) - 1;
                sel[cnt0 + lane] = iw * 64 + b;
                pickrows[buf][lane] = (uint32_t)b;
            }
            if (lane == 0) {
                npickS[buf] = (uint32_t)np;
                if (cnt >= KPOST || iw + 1 >= WORDS) stopF = 1u;
            }
            pm2 = pm1;
            pm1 = pickmask;
        } else {
            // ---------------- workers ----------------
            // 1) commit carried loads (rows of picks(iw-2), target words >= iw+1)
            if (cw0 < WORDS) {
                uint32_t lo = (uint32_t)cv0, hi = (uint32_t)(cv0 >> 32);
                if (lo) atomicOr(&p32[2 * cw0], lo);
                if (hi) atomicOr(&p32[2 * cw0 + 1], hi);
            }
            if (cw1 < WORDS) {
                uint32_t lo = (uint32_t)cv1, hi = (uint32_t)(cv1 >> 32);
                if (lo) atomicOr(&p32[2 * cw1], lo);
                if (hi) atomicOr(&p32[2 * cw1 + 1], hi);
            }
            if (cw2 < WORDS) {
                uint32_t lo = (uint32_t)cv2, hi = (uint32_t)(cv2 >> 32);
                if (lo) atomicOr(&p32[2 * cw2], lo);
                if (hi) atomicOr(&p32[2 * cw2 + 1], hi);
            }
            cw0 = cw1 = cw2 = WORDS;
            // 2) prefetch bands for word iw+1
            if (iw + 1 < WORDS) {
                const int nb = buf ^ 1;
                if (wv == 13) dbuf[nb][lane]  = diagband[(iw + 1) * 64 + lane];
                if (wv == 14) b1buf[nb][lane] = band1[(iw + 1) * 64 + lane];
                if (wv == 15) b2buf[nb][lane] = band2[(iw + 1) * 64 + lane];
            }
            // 3) issue deferred loads for picks(iw-1): words >= (iw-1)+3
            if (iw >= 1) {
                const int pbuf = (iw - 1) & 1;
                const int npk = (int)npickS[pbuf];
                int j = wv - 1;
                if (j < npk) {
                    const int base = iw + 2;
                    const int w0 = base + lane, w1 = w0 + 64, w2 = w1 + 64;
                    {
                        const uint64_t* row =
                            mask + (size_t)((iw - 1) * 64 + pickrows[pbuf][j]) * WORDS;
                        cv0 = (w0 < WORDS) ? row[w0] : 0ull;
                        cv1 = (w1 < WORDS) ? row[w1] : 0ull;
                        cv2 = (w2 < WORDS) ? row[w2] : 0ull;
                        cw0 = (w0 < WORDS) ? w0 : WORDS;
                        cw1 = (w1 < WORDS) ? w1 : WORDS;
                        cw2 = (w2 < WORDS) ? w2 : WORDS;
                    }
                    // overflow picks (>15 in one word, rare): synchronous
                    for (j += 15; j < npk; j += 15) {
                        const uint64_t* row =
                            mask + (size_t)((iw - 1) * 64 + pickrows[pbuf][j]) * WORDS;
                        uint64_t v0 = (w0 < WORDS) ? row[w0] : 0ull;
                        uint64_t v1 = (w1 < WORDS) ? row[w1] : 0ull;
                        uint64_t v2 = (w2 < WORDS) ? row[w2] : 0ull;
                        if (v0) {
                            uint32_t lo = (uint32_t)v0, hi = (uint32_t)(v0 >> 32);
                            if (lo) atomicOr(&p32[2 * w0], lo);
                            if (hi) atomicOr(&p32[2 * w0 + 1], hi);
                        }
                        if (v1) {
                            uint32_t lo = (uint32_t)v1, hi = (uint32_t)(v1 >> 32);
                            if (lo) atomicOr(&p32[2 * w1], lo);
                            if (hi) atomicOr(&p32[2 * w1 + 1], hi);
                        }
                        if (v2) {
                            uint32_t lo = (uint32_t)v2, hi = (uint32_t)(v2 >> 32);
                            if (lo) atomicOr(&p32[2 * w2], lo);
                            if (hi) atomicOr(&p32[2 * w2 + 1], hi);
                        }
                    }
                }
            }
        }
        // raw barrier: drain LDS ops only; global loads stay in flight (T4)
        asm volatile("s_waitcnt lgkmcnt(0)" ::: "memory");
        __builtin_amdgcn_s_barrier();
        asm volatile("" ::: "memory");
        if (stopF) break;
    }
    if (tid == 0) state[6] = (uint32_t)cnt;
}

__global__ void k_gather(const float* __restrict__ bx0, const float* __restrict__ by0,
                         const float* __restrict__ bx1, const float* __restrict__ by1,
                         const int* __restrict__ sel, const uint32_t* __restrict__ state,
                         float4* __restrict__ out)
{
    int slot = blockIdx.x * blockDim.x + threadIdx.x;
    if (slot >= KPOST) return;
    uint32_t cnt = state[6];
    float4 v = make_float4(0.f, 0.f, 0.f, 0.f);
    if ((uint32_t)slot < cnt) {
        int i = sel[slot];
        v = make_float4(bx0[i], by0[i], bx1[i], by1[i]);
    }
    out[slot] = v;
}

extern "C" void kernel_launch(void* const* d_in, const int* in_sizes, int n_in,
                              void* d_out, int out_size, void* d_ws, size_t ws_size,
                              hipStream_t stream)
{
    const float* delta = (const float*)d_in[0];
    const float* score = (const float*)d_in[1];
    float4* out = (float4*)d_out;

    uint8_t* p = (uint8_t*)d_ws;
    auto alloc = [&](size_t bytes) -> void* {
        void* r = (void*)p;
        p += (bytes + 255) & ~(size_t)255;
        return r;
    };
    uint32_t* keys          = (uint32_t*)alloc((size_t)N_TOTAL * 4);
    uint32_t* hist1         = (uint32_t*)alloc(2048 * 4);
    uint32_t* hist2         = (uint32_t*)alloc(2048 * 4);
    uint32_t* hist3         = (uint32_t*)alloc(1024 * 4);
    uint32_t* state         = (uint32_t*)alloc(64);
    uint64_t* cand          = (uint64_t*)alloc((size_t)CAND_CAP * 8);
    uint32_t* sorted_anchor = (uint32_t*)alloc((size_t)NPAD * 4);
    float*    bx0           = (float*)alloc((size_t)NPAD * 4);
    float*    by0           = (float*)alloc((size_t)NPAD * 4);
    float*    bx1           = (float*)alloc((size_t)NPAD * 4);
    float*    by1           = (float*)alloc((size_t)NPAD * 4);
    float*    bar           = (float*)alloc((size_t)NPAD * 4);
    int*      sel           = (int*)alloc((size_t)KPOST * 4);
    uint64_t* diagband      = (uint64_t*)alloc((size_t)NPAD * 8);
    uint64_t* band1         = (uint64_t*)alloc((size_t)NPAD * 8);
    uint64_t* band2         = (uint64_t*)alloc((size_t)NPAD * 8);
    uint64_t* mask          = (uint64_t*)alloc((size_t)NPAD * WORDS * 8);
    (void)ws_size; (void)n_in; (void)in_sizes; (void)out_size;

    const int B = 256;
    const int gN = (N_TOTAL + B - 1) / B;

    hipLaunchKernelGGL(k_init, dim3(68), dim3(B), 0, stream,
                       hist1, hist2, hist3, state, sorted_anchor, band1, band2);
    hipLaunchKernelGGL(k_keys, dim3(gN), dim3(B), 0, stream, delta, score, keys, hist1);
    hipLaunchKernelGGL(k_scan, dim3(1), dim3(B), 0, stream, hist1, state, 2048, 0);
    hipLaunchKernelGGL(k_hist2, dim3(gN), dim3(B), 0, stream, keys, state, hist2);
    hipLaunchKernelGGL(k_scan, dim3(1), dim3(B), 0, stream, hist2, state, 2048, 1);
    hipLaunchKernelGGL(k_hist3, dim3(gN), dim3(B), 0, stream, keys, state, hist3);
    hipLaunchKernelGGL(k_scan, dim3(1), dim3(B), 0, stream, hist3, state, 1024, 2);
    hipLaunchKernelGGL(k_compact, dim3(gN), dim3(B), 0, stream, keys, state, cand);
    hipLaunchKernelGGL(k_ranksort, dim3(CAND_CAP / B), dim3(B), 0, stream,
                       cand, state, sorted_anchor);
    hipLaunchKernelGGL(k_boxes, dim3(NPAD / B), dim3(B), 0, stream,
                       delta, sorted_anchor, bx0, by0, bx1, by1, bar);
    hipLaunchKernelGGL(k_mask, dim3(NPAD / 64, 4), dim3(B), 0, stream,
                       bx0, by0, bx1, by1, bar, mask, diagband, band1, band2);
    hipLaunchKernelGGL(k_nms, dim3(1), dim3(1024), 0, stream,
                       mask, diagband, band1, band2, sel, state);
    hipLaunchKernelGGL(k_gather, dim3((KPOST + B - 1) / B), dim3(B), 0, stream,
                       bx0, by0, bx1, by1, sel, state, out);
}